// Round 12
// baseline (75.052 us; speedup 1.0000x reference)
//
#include <hip/hip_runtime.h>

#define N_NODES 100000
#define N_EDGES 1600000
#define IN_DIM  256
#define OUT_DIM 64

typedef __attribute__((ext_vector_type(8))) short bf16x8;   // 8 bf16 in 4 VGPRs
typedef __attribute__((ext_vector_type(4))) float f32x4;    // MFMA accumulator
typedef __attribute__((ext_vector_type(4))) unsigned u32x4; // 16B gather

// float -> bf16 (round-to-nearest-even)
__device__ __forceinline__ short f2bf(float f) {
    union { float f; unsigned u; } v; v.f = f;
    unsigned r = v.u + 0x7fffu + ((v.u >> 16) & 1u);
    return (short)(r >> 16);
}

// ---------------------------------------------------------------------------
// GEMM via bf16 MFMA: h = x @ w, stored bf16. (~19 us, near its HBM floor.)
// Unchanged from R11 (plain cached loads).
// ---------------------------------------------------------------------------
#define WB_STRIDE 264   // bf16 elems per n-row: 256 + 8 pad

__global__ __launch_bounds__(256)
void gcn_gemm_mfma(const float* __restrict__ x,
                   const float* __restrict__ w,
                   unsigned short* __restrict__ hb)
{
    __shared__ short wb[OUT_DIM * WB_STRIDE];   // 33792 B

    for (int idx = threadIdx.x; idx < IN_DIM * OUT_DIM; idx += 256) {
        int k = idx >> 6;
        int n = idx & 63;
        wb[n * WB_STRIDE + k] = f2bf(w[idx]);
    }
    __syncthreads();

    const int lane = threadIdx.x & 63;
    const int wv   = threadIdx.x >> 6;
    const int r0   = blockIdx.x * 64 + wv * 16;

    const int arow   = r0 + (lane & 15);
    const int arow_c = arow < N_NODES ? arow : N_NODES - 1;
    const int kbase  = (lane >> 4) << 3;                    // 0,8,16,24
    const float* xr  = x + (size_t)arow_c * IN_DIM + kbase;

    const int nlo = lane & 15;
    const short* wb0 = &wb[(0  + nlo) * WB_STRIDE + kbase];
    const short* wb1 = &wb[(16 + nlo) * WB_STRIDE + kbase];
    const short* wb2 = &wb[(32 + nlo) * WB_STRIDE + kbase];
    const short* wb3 = &wb[(48 + nlo) * WB_STRIDE + kbase];

    f32x4 acc0 = {0.f, 0.f, 0.f, 0.f};
    f32x4 acc1 = {0.f, 0.f, 0.f, 0.f};
    f32x4 acc2 = {0.f, 0.f, 0.f, 0.f};
    f32x4 acc3 = {0.f, 0.f, 0.f, 0.f};

#pragma unroll
    for (int k0 = 0; k0 < IN_DIM; k0 += 32) {
        f32x4 f0 = *(const f32x4*)(xr + k0);
        f32x4 f1 = *(const f32x4*)(xr + k0 + 4);
        bf16x8 a;
        a[0] = f2bf(f0.x); a[1] = f2bf(f0.y); a[2] = f2bf(f0.z); a[3] = f2bf(f0.w);
        a[4] = f2bf(f1.x); a[5] = f2bf(f1.y); a[6] = f2bf(f1.z); a[7] = f2bf(f1.w);

        bf16x8 b0 = *(const bf16x8*)(wb0 + k0);
        bf16x8 b1 = *(const bf16x8*)(wb1 + k0);
        bf16x8 b2 = *(const bf16x8*)(wb2 + k0);
        bf16x8 b3 = *(const bf16x8*)(wb3 + k0);

        acc0 = __builtin_amdgcn_mfma_f32_16x16x32_bf16(a, b0, acc0, 0, 0, 0);
        acc1 = __builtin_amdgcn_mfma_f32_16x16x32_bf16(a, b1, acc1, 0, 0, 0);
        acc2 = __builtin_amdgcn_mfma_f32_16x16x32_bf16(a, b2, acc2, 0, 0, 0);
        acc3 = __builtin_amdgcn_mfma_f32_16x16x32_bf16(a, b3, acc3, 0, 0, 0);
    }

    const int crow0 = r0 + ((lane >> 4) << 2);
#pragma unroll
    for (int rr = 0; rr < 4; ++rr) {
        int row = crow0 + rr;
        if (row < N_NODES) {
            unsigned short* hp = hb + (size_t)row * OUT_DIM + nlo;
            hp[0]  = (unsigned short)f2bf(acc0[rr]);
            hp[16] = (unsigned short)f2bf(acc1[rr]);
            hp[32] = (unsigned short)f2bf(acc2[rr]);
            hp[48] = (unsigned short)f2bf(acc3[rr]);
        }
    }
}

// ---------------------------------------------------------------------------
// One-time CSR boundary build (parallel; rows[] L2-resident). ~2-3 us.
// ---------------------------------------------------------------------------
__global__ __launch_bounds__(256)
void build_row_starts(const int* __restrict__ rows, int* __restrict__ starts)
{
    int r = blockIdx.x * 256 + threadIdx.x;
    if (r > N_NODES) return;
    int lo = 0, hi = N_EDGES;
    while (lo < hi) {
        int mid = (lo + hi) >> 1;
        if (rows[mid] < r) lo = mid + 1; else hi = mid;
    }
    starts[r] = lo;
}

// ---------------------------------------------------------------------------
// SpMM + ReLU, WIDE-GATHER variant: 8 edges per global_load_dwordx4.
// lane = grp*8 + sl: grp in [0,8) = which edge of the 8-group this lane
// serves; sl in [0,8) = which 16B slice (8 bf16 dims) of that edge's h-row.
// One wave instruction = 64 lanes x 16B = 1KB = 8 full h-rows (8 lines) in
// flight per queue entry, vs 2 previously. Row-end: 3-step shfl_xor(8/16/32)
// allreduce over grp; lanes 0-7 store 2 x float4.
// ---------------------------------------------------------------------------
#define SPMM_ROWS_PER_BLOCK 32
#define SEG_CAP 1024   // mean edges/block = 512, sd ~23; fallback if exceeded

__global__ __launch_bounds__(256, 2)
void gcn_spmm_wide(const unsigned short* __restrict__ hb,
                   const float* __restrict__ vals,
                   const int* __restrict__ row_starts,
                   const int* __restrict__ cols,
                   float* __restrict__ out)
{
    __shared__ int   starts[SPMM_ROWS_PER_BLOCK + 1];
    __shared__ uint2 s_ec[SEG_CAP];   // .x = val bits, .y = col

    const int row0 = blockIdx.x * SPMM_ROWS_PER_BLOCK;
    const int t    = threadIdx.x;

    if (t <= SPMM_ROWS_PER_BLOCK) {
        starts[t] = row_starts[row0 + t];
    }
    __syncthreads();

    const int seg0   = starts[0];
    const int segLen = starts[SPMM_ROWS_PER_BLOCK] - seg0;
    const bool fits  = (segLen <= SEG_CAP);

    if (fits) {
        for (int i = t; i < segLen; i += 256) {
            s_ec[i] = make_uint2(__float_as_uint(vals[seg0 + i]),
                                 (unsigned)cols[seg0 + i]);
        }
    }
    __syncthreads();

    const int lane = t & 63;
    const int wv   = t >> 6;
    const int grp  = lane >> 3;               // edge-in-group 0..7
    const int sl   = lane & 7;                // dim slice: dims [sl*8, sl*8+8)
    const unsigned off16 = (unsigned)(sl << 4);   // byte offset within h row
    const char* hbase = (const char*)hb;

#define FMA8(v_, h_)                                                        \
    {                                                                       \
        a0 = fmaf(v_, __uint_as_float((h_).x << 16),         a0);           \
        a1 = fmaf(v_, __uint_as_float((h_).x & 0xffff0000u), a1);           \
        a2 = fmaf(v_, __uint_as_float((h_).y << 16),         a2);           \
        a3 = fmaf(v_, __uint_as_float((h_).y & 0xffff0000u), a3);           \
        a4 = fmaf(v_, __uint_as_float((h_).z << 16),         a4);           \
        a5 = fmaf(v_, __uint_as_float((h_).z & 0xffff0000u), a5);           \
        a6 = fmaf(v_, __uint_as_float((h_).w << 16),         a6);           \
        a7 = fmaf(v_, __uint_as_float((h_).w & 0xffff0000u), a7);           \
    }

    for (int rr = wv; rr < SPMM_ROWS_PER_BLOCK; rr += 4) {
        const int r    = row0 + rr;           // N_NODES % 32 == 0, no row tail
        const int s    = starts[rr]     - seg0;
        const int n    = starts[rr + 1] - seg0 - s;
        const int tc8  = n >> 3;              // full 8-edge groups
        const int tail = n & 7;

        float a0 = 0.f, a1 = 0.f, a2 = 0.f, a3 = 0.f;
        float a4 = 0.f, a5 = 0.f, a6 = 0.f, a7 = 0.f;

        if (fits) {
            int i = 0;
            // ---- 2-deep batch of 8-edge groups (2KB in flight) ----
            for (; i + 2 <= tc8; i += 2) {
                uint2 vcA = s_ec[s + (i + 0) * 8 + grp];
                uint2 vcB = s_ec[s + (i + 1) * 8 + grp];
                u32x4 hA = *(const u32x4*)(hbase + ((vcA.y << 7) + off16));
                u32x4 hB = *(const u32x4*)(hbase + ((vcB.y << 7) + off16));
                float vA = __uint_as_float(vcA.x);
                float vB = __uint_as_float(vcB.x);
                FMA8(vA, hA)
                FMA8(vB, hB)
            }
            // ---- single remaining full group ----
            if (i < tc8) {
                uint2 vc = s_ec[s + i * 8 + grp];
                u32x4 h  = *(const u32x4*)(hbase + ((vc.y << 7) + off16));
                float v  = __uint_as_float(vc.x);
                FMA8(v, h)
            }
            // ---- tail group (<8 edges), predicated ----
            if (tail) {
                bool ok  = grp < tail;
                int eidx = s + tc8 * 8 + (ok ? grp : 0);
                uint2 vc = s_ec[eidx];
                float v  = ok ? __uint_as_float(vc.x) : 0.f;
                u32x4 h  = *(const u32x4*)(hbase + ((vc.y << 7) + off16));
                FMA8(v, h)
            }
        } else {
            // overflow fallback (essentially never): global edge reads
            for (int i = 0; i < tc8 + (tail ? 1 : 0); ++i) {
                int base = s + i * 8;
                int lim  = (i < tc8) ? 8 : tail;
                bool ok  = grp < lim;
                int gi   = seg0 + base + (ok ? grp : 0);
                float v  = ok ? vals[gi] : 0.f;
                unsigned c = (unsigned)cols[gi];
                u32x4 h  = *(const u32x4*)(hbase + ((c << 7) + off16));
                FMA8(v, h)
            }
        }

        // ---- allreduce over grp: lanes differing in bits 3..5 ----
        a0 += __shfl_xor(a0, 8);  a0 += __shfl_xor(a0, 16);  a0 += __shfl_xor(a0, 32);
        a1 += __shfl_xor(a1, 8);  a1 += __shfl_xor(a1, 16);  a1 += __shfl_xor(a1, 32);
        a2 += __shfl_xor(a2, 8);  a2 += __shfl_xor(a2, 16);  a2 += __shfl_xor(a2, 32);
        a3 += __shfl_xor(a3, 8);  a3 += __shfl_xor(a3, 16);  a3 += __shfl_xor(a3, 32);
        a4 += __shfl_xor(a4, 8);  a4 += __shfl_xor(a4, 16);  a4 += __shfl_xor(a4, 32);
        a5 += __shfl_xor(a5, 8);  a5 += __shfl_xor(a5, 16);  a5 += __shfl_xor(a5, 32);
        a6 += __shfl_xor(a6, 8);  a6 += __shfl_xor(a6, 16);  a6 += __shfl_xor(a6, 32);
        a7 += __shfl_xor(a7, 8);  a7 += __shfl_xor(a7, 16);  a7 += __shfl_xor(a7, 32);

        if (grp == 0) {
            f32x4 o0, o1;
            o0.x = fmaxf(a0, 0.f); o0.y = fmaxf(a1, 0.f);
            o0.z = fmaxf(a2, 0.f); o0.w = fmaxf(a3, 0.f);
            o1.x = fmaxf(a4, 0.f); o1.y = fmaxf(a5, 0.f);
            o1.z = fmaxf(a6, 0.f); o1.w = fmaxf(a7, 0.f);
            float* op = out + (size_t)r * OUT_DIM + (sl << 3);
            *(f32x4*)(op)     = o0;
            *(f32x4*)(op + 4) = o1;
        }
    }
#undef FMA8
}

// ---------------------------------------------------------------------------
extern "C" void kernel_launch(void* const* d_in, const int* in_sizes, int n_in,
                              void* d_out, int out_size, void* d_ws, size_t ws_size,
                              hipStream_t stream)
{
    const float* x    = (const float*)d_in[0];
    const float* w    = (const float*)d_in[1];
    const float* vals = (const float*)d_in[2];
    const int*   rows = (const int*)d_in[3];
    const int*   cols = (const int*)d_in[4];
    float*       out  = (float*)d_out;

    // workspace layout: [ hb: 12.8 MB bf16 ][ row_starts: 100001 ints ]
    unsigned short* hb = (unsigned short*)d_ws;
    int* row_starts = (int*)((char*)d_ws + (size_t)N_NODES * OUT_DIM * sizeof(unsigned short));

    build_row_starts<<<(N_NODES + 1 + 255) / 256, 256, 0, stream>>>(rows, row_starts);

    const int gemm_grid = (N_NODES + 63) / 64;
    gcn_gemm_mfma<<<gemm_grid, 256, 0, stream>>>(x, w, hb);

    const int spmm_grid = (N_NODES + SPMM_ROWS_PER_BLOCK - 1) / SPMM_ROWS_PER_BLOCK;
    gcn_spmm_wide<<<spmm_grid, 256, 0, stream>>>(hb, vals, row_starts, cols, out);
}

// Round 13
// 66.324 us; speedup vs baseline: 1.1316x; 1.1316x over previous
//
#include <hip/hip_runtime.h>

#define N_NODES 100000
#define N_EDGES 1600000
#define IN_DIM  256
#define OUT_DIM 64

#define GEMM_BLOCKS   1563   // ceil(100000/64)
#define STARTS_BLOCKS 392    // ceil(100001/256)

typedef __attribute__((ext_vector_type(8))) short bf16x8;   // 8 bf16 in 4 VGPRs
typedef __attribute__((ext_vector_type(4))) float f32x4;    // MFMA accumulator

// float -> bf16 (round-to-nearest-even)
__device__ __forceinline__ short f2bf(float f) {
    union { float f; unsigned u; } v; v.f = f;
    unsigned r = v.u + 0x7fffu + ((v.u >> 16) & 1u);
    return (short)(r >> 16);
}

// ---------------------------------------------------------------------------
// Fused kernel 1: GEMM (h = x @ w, bf16 out) + CSR boundary build.
// Blocks [0, GEMM_BLOCKS) do the MFMA GEMM (~19 us, at its HBM floor);
// blocks [GEMM_BLOCKS, +STARTS_BLOCKS) do the parallel lower_bound over
// rows[] (L2-resident, 21 steps). Merging removes one serialized launch.
// ---------------------------------------------------------------------------
#define WB_STRIDE 264   // bf16 elems per n-row: 256 + 8 pad

__global__ __launch_bounds__(256)
void gcn_gemm_and_starts(const float* __restrict__ x,
                         const float* __restrict__ w,
                         unsigned short* __restrict__ hb,
                         const int* __restrict__ rows,
                         int* __restrict__ row_starts)
{
    if (blockIdx.x >= GEMM_BLOCKS) {
        // ---- row_starts builder ----
        int r = (blockIdx.x - GEMM_BLOCKS) * 256 + threadIdx.x;
        if (r <= N_NODES) {
            int lo = 0, hi = N_EDGES;
            while (lo < hi) {
                int mid = (lo + hi) >> 1;
                if (rows[mid] < r) lo = mid + 1; else hi = mid;
            }
            row_starts[r] = lo;
        }
        return;
    }

    // ---- GEMM body ----
    __shared__ short wb[OUT_DIM * WB_STRIDE];   // 33792 B

    for (int idx = threadIdx.x; idx < IN_DIM * OUT_DIM; idx += 256) {
        int k = idx >> 6;
        int n = idx & 63;
        wb[n * WB_STRIDE + k] = f2bf(w[idx]);
    }
    __syncthreads();

    const int lane = threadIdx.x & 63;
    const int wv   = threadIdx.x >> 6;
    const int r0   = blockIdx.x * 64 + wv * 16;

    const int arow   = r0 + (lane & 15);
    const int arow_c = arow < N_NODES ? arow : N_NODES - 1;
    const int kbase  = (lane >> 4) << 3;                    // 0,8,16,24
    const float* xr  = x + (size_t)arow_c * IN_DIM + kbase;

    const int nlo = lane & 15;
    const short* wb0 = &wb[(0  + nlo) * WB_STRIDE + kbase];
    const short* wb1 = &wb[(16 + nlo) * WB_STRIDE + kbase];
    const short* wb2 = &wb[(32 + nlo) * WB_STRIDE + kbase];
    const short* wb3 = &wb[(48 + nlo) * WB_STRIDE + kbase];

    f32x4 acc0 = {0.f, 0.f, 0.f, 0.f};
    f32x4 acc1 = {0.f, 0.f, 0.f, 0.f};
    f32x4 acc2 = {0.f, 0.f, 0.f, 0.f};
    f32x4 acc3 = {0.f, 0.f, 0.f, 0.f};

#pragma unroll
    for (int k0 = 0; k0 < IN_DIM; k0 += 32) {
        f32x4 f0 = *(const f32x4*)(xr + k0);
        f32x4 f1 = *(const f32x4*)(xr + k0 + 4);
        bf16x8 a;
        a[0] = f2bf(f0.x); a[1] = f2bf(f0.y); a[2] = f2bf(f0.z); a[3] = f2bf(f0.w);
        a[4] = f2bf(f1.x); a[5] = f2bf(f1.y); a[6] = f2bf(f1.z); a[7] = f2bf(f1.w);

        bf16x8 b0 = *(const bf16x8*)(wb0 + k0);
        bf16x8 b1 = *(const bf16x8*)(wb1 + k0);
        bf16x8 b2 = *(const bf16x8*)(wb2 + k0);
        bf16x8 b3 = *(const bf16x8*)(wb3 + k0);

        acc0 = __builtin_amdgcn_mfma_f32_16x16x32_bf16(a, b0, acc0, 0, 0, 0);
        acc1 = __builtin_amdgcn_mfma_f32_16x16x32_bf16(a, b1, acc1, 0, 0, 0);
        acc2 = __builtin_amdgcn_mfma_f32_16x16x32_bf16(a, b2, acc2, 0, 0, 0);
        acc3 = __builtin_amdgcn_mfma_f32_16x16x32_bf16(a, b3, acc3, 0, 0, 0);
    }

    const int crow0 = r0 + ((lane >> 4) << 2);
#pragma unroll
    for (int rr = 0; rr < 4; ++rr) {
        int row = crow0 + rr;
        if (row < N_NODES) {
            unsigned short* hp = hb + (size_t)row * OUT_DIM + nlo;
            hp[0]  = (unsigned short)f2bf(acc0[rr]);
            hp[16] = (unsigned short)f2bf(acc1[rr]);
            hp[32] = (unsigned short)f2bf(acc2[rr]);
            hp[48] = (unsigned short)f2bf(acc3[rr]);
        }
    }
}

// ---------------------------------------------------------------------------
// SpMM + ReLU (R11 structure, best 72.9 us total). Half-wave pairing,
// de-predicated full-pair loop, 32-bit offsets, agent-scope gathers.
// ONLY change vs R11: edge staging (vals/cols, streamed exactly once) is
// nt-loaded so it doesn't evict h lines from L2 during the gather phase.
// ---------------------------------------------------------------------------
#define SPMM_ROWS_PER_BLOCK 32
#define SEG_CAP 1024   // mean edges/block = 512, sd ~23; fallback if exceeded

__device__ __forceinline__ unsigned gather_l2(const void* p) {
    return __hip_atomic_load((const unsigned*)p, __ATOMIC_RELAXED,
                             __HIP_MEMORY_SCOPE_AGENT);
}

__global__ __launch_bounds__(256, 2)
void gcn_spmm_relu_kernel(const unsigned short* __restrict__ hb,
                          const float* __restrict__ vals,
                          const int* __restrict__ row_starts,
                          const int* __restrict__ cols,
                          float* __restrict__ out)
{
    __shared__ int   starts[SPMM_ROWS_PER_BLOCK + 1];
    __shared__ uint2 s_ec[SEG_CAP];   // .x = val bits, .y = col

    const int row0 = blockIdx.x * SPMM_ROWS_PER_BLOCK;
    const int t    = threadIdx.x;

    if (t <= SPMM_ROWS_PER_BLOCK) {
        starts[t] = row_starts[row0 + t];
    }
    __syncthreads();

    const int seg0   = starts[0];
    const int segLen = starts[SPMM_ROWS_PER_BLOCK] - seg0;
    const bool fits  = (segLen <= SEG_CAP);

    if (fits) {
        for (int i = t; i < segLen; i += 256) {
            unsigned vbits = __float_as_uint(__builtin_nontemporal_load(&vals[seg0 + i]));
            unsigned cbits = (unsigned)__builtin_nontemporal_load(&cols[seg0 + i]);
            s_ec[i] = make_uint2(vbits, cbits);
        }
    }
    __syncthreads();

    const int lane = t & 63;
    const int wv   = t >> 6;
    const int half = lane >> 5;             // 0: even edges, 1: odd edges
    const int sub  = lane & 31;             // dim pair: dims 2*sub, 2*sub+1
    const unsigned sub4 = (unsigned)(sub << 2);
    const char* hbase = (const char*)hb;

#define GATHER(vc_) gather_l2(hbase + (((vc_).y << 7) + sub4))
#define LO16(hx_)   __uint_as_float((hx_) << 16)
#define HI16(hx_)   __uint_as_float((hx_) & 0xffff0000u)

    for (int rr = wv; rr < SPMM_ROWS_PER_BLOCK; rr += 4) {
        const int r = row0 + rr;                   // N_NODES % 32 == 0, no tail
        const int s = starts[rr]     - seg0;
        const int e = starts[rr + 1] - seg0;
        const int n  = e - s;
        const int fp = n >> 1;                     // full pairs: no predication

        float aL[4] = {0.f, 0.f, 0.f, 0.f};
        float aH[4] = {0.f, 0.f, 0.f, 0.f};

        if (fits) {
            const int sb = s + half;
            int i = 0;
            // ---- 8-deep batch: 8 gathers in flight, zero predication ----
            for (; i + 8 <= fp; i += 8) {
                float    vv[8];
                unsigned hx[8];
#pragma unroll
                for (int g = 0; g < 8; ++g) {
                    uint2 vc = s_ec[sb + 2 * (i + g)];
                    vv[g] = __uint_as_float(vc.x);
                    hx[g] = GATHER(vc);
                }
#pragma unroll
                for (int g = 0; g < 8; ++g) {
                    aL[g & 3] = fmaf(vv[g], LO16(hx[g]), aL[g & 3]);
                    aH[g & 3] = fmaf(vv[g], HI16(hx[g]), aH[g & 3]);
                }
            }
            // ---- 4-deep batch ----
            if (i + 4 <= fp) {
                float    vv[4];
                unsigned hx[4];
#pragma unroll
                for (int g = 0; g < 4; ++g) {
                    uint2 vc = s_ec[sb + 2 * (i + g)];
                    vv[g] = __uint_as_float(vc.x);
                    hx[g] = GATHER(vc);
                }
#pragma unroll
                for (int g = 0; g < 4; ++g) {
                    aL[g] = fmaf(vv[g], LO16(hx[g]), aL[g]);
                    aH[g] = fmaf(vv[g], HI16(hx[g]), aH[g]);
                }
                i += 4;
            }
            // ---- remaining full pairs ----
            for (; i < fp; ++i) {
                uint2 vc = s_ec[sb + 2 * i];
                float v  = __uint_as_float(vc.x);
                unsigned hx = GATHER(vc);
                aL[0] = fmaf(v, LO16(hx), aL[0]);
                aH[0] = fmaf(v, HI16(hx), aH[0]);
            }
            // ---- odd tail: one predicated step (half==0 lanes contribute) ----
            if (n & 1) {
                uint2 vc = s_ec[s + n - 1];              // uniform broadcast read
                float v  = (half == 0) ? __uint_as_float(vc.x) : 0.f;
                unsigned hx = GATHER(vc);
                aL[0] = fmaf(v, LO16(hx), aL[0]);
                aH[0] = fmaf(v, HI16(hx), aH[0]);
            }
        } else {
            // overflow fallback (essentially never): global reads, predicated
            const int tc = (n + 1) >> 1;
            for (int i = 0; i < tc; ++i) {
                int ei   = s + 2 * i + half;
                bool ok  = ei < e;
                int eidx = (ok ? ei : e - 1) + seg0;
                float v  = ok ? vals[eidx] : 0.f;
                uint2 vc = make_uint2(0u, (unsigned)cols[eidx]);
                unsigned hx = GATHER(vc);
                aL[0] = fmaf(v, LO16(hx), aL[0]);
                aH[0] = fmaf(v, HI16(hx), aH[0]);
            }
        }

        float lo = (aL[0] + aL[1]) + (aL[2] + aL[3]);
        float hi = (aH[0] + aH[1]) + (aH[2] + aH[3]);
        lo += __shfl_xor(lo, 32);
        hi += __shfl_xor(hi, 32);

        if (half == 0) {
            float2 o;
            o.x = fmaxf(lo, 0.f);
            o.y = fmaxf(hi, 0.f);
            *(float2*)(out + (size_t)r * OUT_DIM + 2u * sub) = o;   // 256B/half-wave
        }
    }
#undef GATHER
#undef LO16
#undef HI16
}

// ---------------------------------------------------------------------------
extern "C" void kernel_launch(void* const* d_in, const int* in_sizes, int n_in,
                              void* d_out, int out_size, void* d_ws, size_t ws_size,
                              hipStream_t stream)
{
    const float* x    = (const float*)d_in[0];
    const float* w    = (const float*)d_in[1];
    const float* vals = (const float*)d_in[2];
    const int*   rows = (const int*)d_in[3];
    const int*   cols = (const int*)d_in[4];
    float*       out  = (float*)d_out;

    // workspace layout: [ hb: 12.8 MB bf16 ][ row_starts: 100001 ints ]
    unsigned short* hb = (unsigned short*)d_ws;
    int* row_starts = (int*)((char*)d_ws + (size_t)N_NODES * OUT_DIM * sizeof(unsigned short));

    gcn_gemm_and_starts<<<GEMM_BLOCKS + STARTS_BLOCKS, 256, 0, stream>>>(
        x, w, hb, rows, row_starts);

    const int spmm_grid = (N_NODES + SPMM_ROWS_PER_BLOCK - 1) / SPMM_ROWS_PER_BLOCK;
    gcn_spmm_relu_kernel<<<spmm_grid, 256, 0, stream>>>(hb, vals, row_starts, cols, out);
}